// Round 4
// baseline (339.086 us; speedup 1.0000x reference)
//
#include <hip/hip_runtime.h>
#include <hip/hip_bf16.h>
#include <stdint.h>

typedef __attribute__((ext_vector_type(8))) short bf16x8;
typedef __attribute__((ext_vector_type(4))) float f32x4;

#define S_2LOG2E 2.8853900817779268f   // 2*log2(e): tanh(x)=1-2/(2^(x*S)+1)

#if __has_builtin(__builtin_amdgcn_exp2f)
#define EXP2F(x) __builtin_amdgcn_exp2f(x)
#else
#define EXP2F(x) __expf((x) * 0.6931471805599453f)
#endif
#if __has_builtin(__builtin_amdgcn_rcpf)
#define RCPF(x) __builtin_amdgcn_rcpf(x)
#else
#define RCPF(x) (1.0f / (x))
#endif

__device__ __forceinline__ float tanh_fast(float x) {   // prep only
    float e = __expf(2.0f * x);
    return 1.0f - 2.0f / (e + 1.0f);
}

// ---- bf16 pack via native v_cvt_pk_bf16_f32 (RNE) ----
__device__ __forceinline__ bf16x8 pack2(float4 a, float4 b) {
    union { bf16x8 v; __hip_bfloat162 h[4]; } r;
    r.h[0] = __float22bfloat162_rn(make_float2(a.x, a.y));
    r.h[1] = __float22bfloat162_rn(make_float2(a.z, a.w));
    r.h[2] = __float22bfloat162_rn(make_float2(b.x, b.y));
    r.h[3] = __float22bfloat162_rn(make_float2(b.z, b.w));
    return r.v;
}
__device__ __forceinline__ float4 scl4(float4 a) {      // fold S into W at cast time
    a.x *= S_2LOG2E; a.y *= S_2LOG2E; a.z *= S_2LOG2E; a.w *= S_2LOG2E;
    return a;
}
#define MFMA16(a, b, c) __builtin_amdgcn_mfma_f32_16x16x32_bf16((a), (b), (c), 0, 0, 0)

// =========================================================================
// Kernel 1 (prep) — unchanged structure: q, scaled biases, scaled W frags,
// out-zero, bf16 table cast (1 chunk/thread).
// =========================================================================
__global__ void finerec_prep(
    const float* __restrict__ user_emb, const float* __restrict__ attr,
    const float* __restrict__ Wq, const float* __restrict__ bq,
    const float* __restrict__ Wk, const float* __restrict__ bk,
    const float* __restrict__ Wv, const float* __restrict__ bv,
    const float* __restrict__ item_table, const float* __restrict__ opin_table,
    float* __restrict__ q_ws, float* __restrict__ bkz_ws, float* __restrict__ bvz_ws,
    short* __restrict__ wf_ws, short* __restrict__ itb, short* __restrict__ opb,
    float* __restrict__ out, int U, int n_item, int n_opi, int qb)
{
    const int bx = blockIdx.x, tid = threadIdx.x;
    if (bx >= qb + 49) {                     // ---- table cast to bf16 chunks ----
        const int castb = gridDim.x - qb - 49;
        const int gid = (bx - qb - 49) * 256 + tid;
        const int stride = castb * 256;
        const int tci = n_item * 16, tc = (n_item + n_opi) * 16;
        for (int c = gid; c < tc; c += stride) {
            if (c < tci) {
                const float* src = item_table + (size_t)c * 8;
                ((bf16x8*)itb)[c] = pack2(*(const float4*)src, *(const float4*)(src + 4));
            } else {
                const float* src = opin_table + (size_t)(c - tci) * 8;
                ((bf16x8*)opb)[c - tci] = pack2(*(const float4*)src, *(const float4*)(src + 4));
            }
        }
        return;
    }
    if (bx >= qb + 9) {                      // ---- zero the atomic output ----
        const int gid = (bx - qb - 9) * 256 + tid;
        float4 z = {0.0f, 0.0f, 0.0f, 0.0f};
        for (int i = gid; i < U * 32; i += 40 * 256) ((float4*)out)[i] = z;
        return;
    }
    if (bx >= qb + 1) {                      // ---- weight cast (pre-scaled by S) ----
        const int bi = bx - qb - 1;
#pragma unroll
        for (int t = 0; t < 2; ++t) {
            const int g = bi * 512 + t * 256 + tid;           // 0..4095
            const int mat = g >> 11, gg = g & 2047, r = gg >> 4, c = gg & 15;
            const float* src = (mat ? Wv : Wk) + r * 128 + c * 8;
            ((bf16x8*)wf_ws)[(mat << 11) + (r << 4) + (c ^ (r & 15))] =
                pack2(scl4(*(const float4*)src), scl4(*(const float4*)(src + 4)));
        }
        return;
    }
    if (bx == qb) {                          // ---- pre-scaled biases ----
        if (tid < 128) {
            const float* wr = Wk + tid * 128;
            float s = bk[tid];
            for (int k = 0; k < 128; k += 4) {
                float4 w4 = *(const float4*)(wr + k);
                float4 a4 = *(const float4*)(attr + k);
                s += w4.x * a4.x + w4.y * a4.y + w4.z * a4.z + w4.w * a4.w;
            }
            bkz_ws[tid] = s * S_2LOG2E;
        } else if (tid < 256) {
            bvz_ws[tid - 128] = bv[tid - 128] * S_2LOG2E;
        }
        return;
    }
    // ---- q: 64 users per block (16 per wave) ----
    const int wv = tid >> 6, lane = tid & 63;
    const int l15 = lane & 15, quad = lane >> 4;
    const int u0 = (bx * 4 + wv) * 16;
    int ur = u0 + l15; if (ur >= U) ur = U - 1;
    const float* up = user_emb + (size_t)ur * 128 + quad * 8;
    bf16x8 af[4];
#pragma unroll
    for (int ks = 0; ks < 4; ++ks)
        af[ks] = pack2(*(const float4*)(up + ks * 32), *(const float4*)(up + ks * 32 + 4));
#pragma unroll
    for (int nt = 0; nt < 8; ++nt) {
        const int n = nt * 16 + l15;
        const float* wp = Wq + n * 128 + quad * 8;
        f32x4 acc = {0, 0, 0, 0};
#pragma unroll
        for (int ks = 0; ks < 4; ++ks) {
            bf16x8 bf = pack2(*(const float4*)(wp + ks * 32), *(const float4*)(wp + ks * 32 + 4));
            acc = MFMA16(af[ks], bf, acc);
        }
        const float bqv = bq[n];
#pragma unroll
        for (int r = 0; r < 4; ++r) {
            int row = u0 + quad * 4 + r;
            if (row < U) q_ws[row * 128 + nt * 16 + l15] = tanh_fast(acc[r] + bqv);
        }
    }
}

// =========================================================================
// Kernel 2 (main): round-1 memory structure restored (ALL W-frags in LDS,
// chained double-MFMA V pass — round 2 proved VMEM-W and pre-add regress).
// New: (1) kernel-constant W-frag base pointers + fully unrolled nt loops
// -> all DS/global offsets are compile-time immediates (offset:nt*4096 for
// W, +32768 for V-W, nt*64 for q/bias) -> near-zero addressing VALU;
// (2) tanh fold: sum(qa*tanh) = sum(qa) - 2*sum(qa*rcp) -> 1 fma/elem;
// (3) job bookkeeping scalarized via readfirstlane -> SALU + SGPR bases.
// __launch_bounds__(1024,8) pins VGPR<=64 so 2 blocks/CU (32 waves) hold.
// =========================================================================
template<int BF16, int LC>
__global__ __launch_bounds__(1024, 8) void finerec_main(
    const float* __restrict__ item_table, const float* __restrict__ opin_table,
    const int* __restrict__ item_seqs, const int* __restrict__ opin_seqs,
    const float* __restrict__ q_ws, const float* __restrict__ bkz_ws,
    const float* __restrict__ bvz_ws, const short* __restrict__ wf_ws,
    const short* __restrict__ itb, const short* __restrict__ opb,
    float* __restrict__ out, int U, int Lrt)
{
    __shared__ __align__(16) short wlds[32768];   // S*Wk + S*Wv frag chunks
    __shared__ float bkz_lds[128], bvz_lds[128];

    const int L = LC ? LC : Lrt;
    const int tid = threadIdx.x;
    const int wv = tid >> 6, lane = tid & 63, l15 = lane & 15, quad = lane >> 4;

    const bf16x8* wsrc = (const bf16x8*)wf_ws;
    bf16x8* wldsv = (bf16x8*)wlds;
#pragma unroll
    for (int i = 0; i < 4; ++i)
        wldsv[i * 1024 + tid] = wsrc[i * 1024 + tid];
    if (tid < 128)      bkz_lds[tid]       = bkz_ws[tid];
    else if (tid < 256) bvz_lds[tid - 128] = bvz_ws[tid - 128];
    __syncthreads();   // the ONLY block barrier

    // Kernel-constant per-lane bases. Frag idx = nt*256 + l15*16 + ((ks*4+quad)^l15):
    // nt contributes byte offset nt*4096 (K) / 32768+nt*4096 (V) -> DS imm (max 65520).
    const bf16x8* wb0 = (const bf16x8*)wlds + (l15 << 4) + ((0 * 4 + quad) ^ l15);
    const bf16x8* wb1 = (const bf16x8*)wlds + (l15 << 4) + ((1 * 4 + quad) ^ l15);
    const bf16x8* wb2 = (const bf16x8*)wlds + (l15 << 4) + ((2 * 4 + quad) ^ l15);
    const bf16x8* wb3 = (const bf16x8*)wlds + (l15 << 4) + ((3 * 4 + quad) ^ l15);
    const float* bkzb = bkz_lds + l15;            // + nt*16 -> imm nt*64
    const float* bvzb = bvz_lds + l15;

    const int UL = U * L;
    const int njobs = (UL + 15) >> 4;
    const int nwaves = gridDim.x * 16;

#pragma unroll 1
    for (int job = blockIdx.x * 16 + wv; job < njobs; job += nwaves) {
        const int js = __builtin_amdgcn_readfirstlane(job);   // wave-uniform -> SALU
        const int g0 = js << 4;                  // first flattened row
        const int uA = g0 / L;
        const int bb = L - (g0 - uA * L);        // rows of uA in this job
        const bool split = (bb < 16) && (uA + 1 < U);

        int vi = 0, vo = 0;
        if (lane < 16 && g0 + lane < UL) {
            vi = item_seqs[g0 + lane];
            vo = opin_seqs[g0 + lane];
        }
        const unsigned long long mb = __ballot(vi > 0);

        // ---- gather item rows -> A-frags ----
        const int idx = __shfl(vi, l15);
        bf16x8 ai[4];
        if (BF16) {
            const bf16x8* pb = (const bf16x8*)itb + (size_t)idx * 16 + quad;
#pragma unroll
            for (int ks = 0; ks < 4; ++ks) ai[ks] = pb[ks * 4];
        } else {
            const float* p = item_table + (size_t)idx * 128 + quad * 8;
#pragma unroll
            for (int ks = 0; ks < 4; ++ks)
                ai[ks] = pack2(*(const float4*)(p + ks * 32), *(const float4*)(p + ks * 32 + 4));
        }

        const float* qA = q_ws + (size_t)uA * 128 + l15;   // + nt*16 -> imm nt*64

        // ---- K pass: c init = bias; folded tanh: w = sum(q) - 2*sum(q*rcp) ----
        float wacc[4] = {0.0f, 0.0f, 0.0f, 0.0f};
        if (!split) {
            float sq = 0.0f;
#pragma unroll
            for (int nt = 0; nt < 8; ++nt) {
                const float qa = qA[nt * 16];
                const float bz = bkzb[nt * 16];
                f32x4 c = {bz, bz, bz, bz};
                c = MFMA16(ai[0], wb0[nt * 256], c);
                c = MFMA16(ai[1], wb1[nt * 256], c);
                c = MFMA16(ai[2], wb2[nt * 256], c);
                c = MFMA16(ai[3], wb3[nt * 256], c);
                const float m2qa = -2.0f * qa;
                sq += qa;
#pragma unroll
                for (int r = 0; r < 4; ++r) {
                    const float rc = RCPF(EXP2F(c[r]) + 1.0f);
                    wacc[r] = fmaf(m2qa, rc, wacc[r]);
                }
            }
#pragma unroll
            for (int r = 0; r < 4; ++r) wacc[r] += sq;
        } else {
            float sqA = 0.0f, sqB = 0.0f;
#pragma unroll
            for (int nt = 0; nt < 8; ++nt) {
                const float qa  = qA[nt * 16];
                const float qb2 = qA[128 + nt * 16];
                const float bz = bkzb[nt * 16];
                f32x4 c = {bz, bz, bz, bz};
                c = MFMA16(ai[0], wb0[nt * 256], c);
                c = MFMA16(ai[1], wb1[nt * 256], c);
                c = MFMA16(ai[2], wb2[nt * 256], c);
                c = MFMA16(ai[3], wb3[nt * 256], c);
                const float m2qa = -2.0f * qa, m2qb = -2.0f * qb2;
                sqA += qa; sqB += qb2;
#pragma unroll
                for (int r = 0; r < 4; ++r) {
                    const float rc = RCPF(EXP2F(c[r]) + 1.0f);
                    wacc[r] = fmaf((quad * 4 + r < bb) ? m2qa : m2qb, rc, wacc[r]);
                }
            }
#pragma unroll
            for (int r = 0; r < 4; ++r) wacc[r] += (quad * 4 + r < bb) ? sqA : sqB;
        }
        // ---- w: reduce over 16 cols within quad + padding mask ----
        float w[4];
#pragma unroll
        for (int r = 0; r < 4; ++r) {
            float t = wacc[r];
            t += __shfl_xor(t, 1); t += __shfl_xor(t, 2);
            t += __shfl_xor(t, 4); t += __shfl_xor(t, 8);
            w[r] = ((mb >> (quad * 4 + r)) & 1ull) ? t : 0.0f;
        }
        // ---- gather opin rows -> second A-frags (chained MFMA linearity) ----
        const int od = __shfl(vo, l15);
        bf16x8 ao[4];
        if (BF16) {
            const bf16x8* pb = (const bf16x8*)opb + (size_t)od * 16 + quad;
#pragma unroll
            for (int ks = 0; ks < 4; ++ks) ao[ks] = pb[ks * 4];
        } else {
            const float* p = opin_table + (size_t)od * 128 + quad * 8;
#pragma unroll
            for (int ks = 0; ks < 4; ++ks)
                ao[ks] = pack2(*(const float4*)(p + ks * 32), *(const float4*)(p + ks * 32 + 4));
        }
        // ---- V pass: folded tanh: acc = sum(w) - 2*sum(w*rcp) ----
        float m2w[4]; float ws = 0.0f;
#pragma unroll
        for (int r = 0; r < 4; ++r) { m2w[r] = -2.0f * w[r]; ws += w[r]; }
        float* outbase = out + (size_t)uA * 128 + quad * 32 + l15;   // SGPR base + lane off
        if (!split) {
            float s0 = 0.0f, s1 = 0.0f;
#pragma unroll
            for (int nt = 0; nt < 8; ++nt) {
                const float bz = bvzb[nt * 16];
                f32x4 c = {bz, bz, bz, bz};
                {
                    const bf16x8 wf0 = wb0[2048 + nt * 256];
                    c = MFMA16(ai[0], wf0, c); c = MFMA16(ao[0], wf0, c);
                    const bf16x8 wf1 = wb1[2048 + nt * 256];
                    c = MFMA16(ai[1], wf1, c); c = MFMA16(ao[1], wf1, c);
                    const bf16x8 wf2 = wb2[2048 + nt * 256];
                    c = MFMA16(ai[2], wf2, c); c = MFMA16(ao[2], wf2, c);
                    const bf16x8 wf3 = wb3[2048 + nt * 256];
                    c = MFMA16(ai[3], wf3, c); c = MFMA16(ao[3], wf3, c);
                }
                float acc = ws;
#pragma unroll
                for (int r = 0; r < 4; ++r) {
                    const float rc = RCPF(EXP2F(c[r]) + 1.0f);
                    acc = fmaf(m2w[r], rc, acc);
                }
                acc += __shfl_xor(acc, 16);
                acc += __shfl_xor(acc, 32);
                const bool mine = (quad == (nt >> 1));
                s0 += (mine && !(nt & 1)) ? acc : 0.0f;
                s1 += (mine &&  (nt & 1)) ? acc : 0.0f;
            }
            atomicAdd(outbase, s0);
            atomicAdd(outbase + 16, s1);
        } else {
            float m2wA[4]; float wsA = 0.0f;
#pragma unroll
            for (int r = 0; r < 4; ++r) {
                const bool sA = (quad * 4 + r) < bb;
                m2wA[r] = sA ? m2w[r] : 0.0f;
                wsA += sA ? w[r] : 0.0f;
            }
            float sA0 = 0.0f, sA1 = 0.0f, sB0 = 0.0f, sB1 = 0.0f;
#pragma unroll
            for (int nt = 0; nt < 8; ++nt) {
                const float bz = bvzb[nt * 16];
                f32x4 c = {bz, bz, bz, bz};
                {
                    const bf16x8 wf0 = wb0[2048 + nt * 256];
                    c = MFMA16(ai[0], wf0, c); c = MFMA16(ao[0], wf0, c);
                    const bf16x8 wf1 = wb1[2048 + nt * 256];
                    c = MFMA16(ai[1], wf1, c); c = MFMA16(ao[1], wf1, c);
                    const bf16x8 wf2 = wb2[2048 + nt * 256];
                    c = MFMA16(ai[2], wf2, c); c = MFMA16(ao[2], wf2, c);
                    const bf16x8 wf3 = wb3[2048 + nt * 256];
                    c = MFMA16(ai[3], wf3, c); c = MFMA16(ao[3], wf3, c);
                }
                float accT = ws, accA = wsA;
#pragma unroll
                for (int r = 0; r < 4; ++r) {
                    const float rc = RCPF(EXP2F(c[r]) + 1.0f);
                    accT = fmaf(m2w[r],  rc, accT);
                    accA = fmaf(m2wA[r], rc, accA);
                }
                accT += __shfl_xor(accT, 16); accT += __shfl_xor(accT, 32);
                accA += __shfl_xor(accA, 16); accA += __shfl_xor(accA, 32);
                const float accB = accT - accA;
                const bool mine = (quad == (nt >> 1));
                const bool lo = !(nt & 1);
                sA0 += (mine && lo)  ? accA : 0.0f;
                sA1 += (mine && !lo) ? accA : 0.0f;
                sB0 += (mine && lo)  ? accB : 0.0f;
                sB1 += (mine && !lo) ? accB : 0.0f;
            }
            atomicAdd(outbase, sA0);
            atomicAdd(outbase + 16, sA1);
            atomicAdd(outbase + 128, sB0);        // user uA+1
            atomicAdd(outbase + 144, sB1);
        }
    }
}

extern "C" void kernel_launch(void* const* d_in, const int* in_sizes, int n_in,
                              void* d_out, int out_size, void* d_ws, size_t ws_size,
                              hipStream_t stream) {
    const float* item_table = (const float*)d_in[0];
    const float* opin_table = (const float*)d_in[1];
    const float* user_emb   = (const float*)d_in[2];
    const float* attr       = (const float*)d_in[3];
    const float* Wq = (const float*)d_in[4];
    const float* bq = (const float*)d_in[5];
    const float* Wk = (const float*)d_in[6];
    const float* bk = (const float*)d_in[7];
    const float* Wv = (const float*)d_in[8];
    const float* bv = (const float*)d_in[9];
    const int* item_seqs = (const int*)d_in[10];
    const int* opin_seqs = (const int*)d_in[11];
    float* out = (float*)d_out;

    const int U = in_sizes[2] / 128;        // 10000
    const int L = in_sizes[10] / U;         // 50
    const int n_item = in_sizes[0] / 128;   // 50000
    const int n_opi  = in_sizes[1] / 128;   // 5000

    // ---- ws layout ----
    char* w = (char*)d_ws;
    float* q_ws   = (float*)w;               w += (size_t)U * 128 * 4;
    float* bkz_ws = (float*)w;               w += 512;
    float* bvz_ws = (float*)w;               w += 512;
    short* wf_ws  = (short*)w;               w += 4096 * 16;
    short* itb    = (short*)w;               w += (size_t)n_item * 128 * 2;
    short* opb    = (short*)w;               w += (size_t)n_opi * 128 * 2;
    const size_t need = (size_t)(w - (char*)d_ws);
    const int use_bf16 = (ws_size >= need) ? 1 : 0;

    const int qb = (U + 63) / 64;
    const int castb = use_bf16 ? (((n_item + n_opi) * 16 + 255) / 256) : 0;
    const int prep_grid = qb + 49 + castb;
    finerec_prep<<<prep_grid, 256, 0, stream>>>(
        user_emb, attr, Wq, bq, Wk, bk, Wv, bv, item_table, opin_table,
        q_ws, bkz_ws, bvz_ws, wf_ws, itb, opb, out, U, n_item, n_opi, qb);

    if (use_bf16) {
        if (L == 50)
            finerec_main<1, 50><<<512, 1024, 0, stream>>>(
                item_table, opin_table, item_seqs, opin_seqs,
                q_ws, bkz_ws, bvz_ws, wf_ws, itb, opb, out, U, L);
        else
            finerec_main<1, 0><<<512, 1024, 0, stream>>>(
                item_table, opin_table, item_seqs, opin_seqs,
                q_ws, bkz_ws, bvz_ws, wf_ws, itb, opb, out, U, L);
    } else {
        if (L == 50)
            finerec_main<0, 50><<<512, 1024, 0, stream>>>(
                item_table, opin_table, item_seqs, opin_seqs,
                q_ws, bkz_ws, bvz_ws, wf_ws, itb, opb, out, U, L);
        else
            finerec_main<0, 0><<<512, 1024, 0, stream>>>(
                item_table, opin_table, item_seqs, opin_seqs,
                q_ws, bkz_ws, bvz_ws, wf_ws, itb, opb, out, U, L);
    }
}

// Round 5
// 183.053 us; speedup vs baseline: 1.8524x; 1.8524x over previous
//
#include <hip/hip_runtime.h>
#include <hip/hip_bf16.h>
#include <stdint.h>

typedef __attribute__((ext_vector_type(8))) short bf16x8;
typedef __attribute__((ext_vector_type(4))) float f32x4;

#define S_2LOG2E 2.8853900817779268f   // 2*log2(e): tanh(x)=1-2/(2^(x*S)+1)

#if __has_builtin(__builtin_amdgcn_exp2f)
#define EXP2F(x) __builtin_amdgcn_exp2f(x)
#else
#define EXP2F(x) __expf((x) * 0.6931471805599453f)
#endif
#if __has_builtin(__builtin_amdgcn_rcpf)
#define RCPF(x) __builtin_amdgcn_rcpf(x)
#else
#define RCPF(x) (1.0f / (x))
#endif

__device__ __forceinline__ float tanh_fast(float x) {   // prep only
    float e = __expf(2.0f * x);
    return 1.0f - 2.0f / (e + 1.0f);
}

// ---- bf16 pack via native v_cvt_pk_bf16_f32 (RNE) ----
__device__ __forceinline__ bf16x8 pack2(float4 a, float4 b) {
    union { bf16x8 v; __hip_bfloat162 h[4]; } r;
    r.h[0] = __float22bfloat162_rn(make_float2(a.x, a.y));
    r.h[1] = __float22bfloat162_rn(make_float2(a.z, a.w));
    r.h[2] = __float22bfloat162_rn(make_float2(b.x, b.y));
    r.h[3] = __float22bfloat162_rn(make_float2(b.z, b.w));
    return r.v;
}
__device__ __forceinline__ float4 scl4(float4 a) {      // fold S into W at cast time
    a.x *= S_2LOG2E; a.y *= S_2LOG2E; a.z *= S_2LOG2E; a.w *= S_2LOG2E;
    return a;
}
#define MFMA16(a, b, c) __builtin_amdgcn_mfma_f32_16x16x32_bf16((a), (b), (c), 0, 0, 0)

// =========================================================================
// Kernel 1 (prep): q, scaled biases, scaled W frags, out-zero, bf16 table
// cast (1 chunk/thread).
// =========================================================================
__global__ void finerec_prep(
    const float* __restrict__ user_emb, const float* __restrict__ attr,
    const float* __restrict__ Wq, const float* __restrict__ bq,
    const float* __restrict__ Wk, const float* __restrict__ bk,
    const float* __restrict__ Wv, const float* __restrict__ bv,
    const float* __restrict__ item_table, const float* __restrict__ opin_table,
    float* __restrict__ q_ws, float* __restrict__ bkz_ws, float* __restrict__ bvz_ws,
    short* __restrict__ wf_ws, short* __restrict__ itb, short* __restrict__ opb,
    float* __restrict__ out, int U, int n_item, int n_opi, int qb)
{
    const int bx = blockIdx.x, tid = threadIdx.x;
    if (bx >= qb + 49) {                     // ---- table cast to bf16 chunks ----
        const int castb = gridDim.x - qb - 49;
        const int gid = (bx - qb - 49) * 256 + tid;
        const int stride = castb * 256;
        const int tci = n_item * 16, tc = (n_item + n_opi) * 16;
        for (int c = gid; c < tc; c += stride) {
            if (c < tci) {
                const float* src = item_table + (size_t)c * 8;
                ((bf16x8*)itb)[c] = pack2(*(const float4*)src, *(const float4*)(src + 4));
            } else {
                const float* src = opin_table + (size_t)(c - tci) * 8;
                ((bf16x8*)opb)[c - tci] = pack2(*(const float4*)src, *(const float4*)(src + 4));
            }
        }
        return;
    }
    if (bx >= qb + 9) {                      // ---- zero the atomic output ----
        const int gid = (bx - qb - 9) * 256 + tid;
        float4 z = {0.0f, 0.0f, 0.0f, 0.0f};
        for (int i = gid; i < U * 32; i += 40 * 256) ((float4*)out)[i] = z;
        return;
    }
    if (bx >= qb + 1) {                      // ---- weight cast (pre-scaled by S) ----
        const int bi = bx - qb - 1;
#pragma unroll
        for (int t = 0; t < 2; ++t) {
            const int g = bi * 512 + t * 256 + tid;           // 0..4095
            const int mat = g >> 11, gg = g & 2047, r = gg >> 4, c = gg & 15;
            const float* src = (mat ? Wv : Wk) + r * 128 + c * 8;
            ((bf16x8*)wf_ws)[(mat << 11) + (r << 4) + (c ^ (r & 15))] =
                pack2(scl4(*(const float4*)src), scl4(*(const float4*)(src + 4)));
        }
        return;
    }
    if (bx == qb) {                          // ---- pre-scaled biases ----
        if (tid < 128) {
            const float* wr = Wk + tid * 128;
            float s = bk[tid];
            for (int k = 0; k < 128; k += 4) {
                float4 w4 = *(const float4*)(wr + k);
                float4 a4 = *(const float4*)(attr + k);
                s += w4.x * a4.x + w4.y * a4.y + w4.z * a4.z + w4.w * a4.w;
            }
            bkz_ws[tid] = s * S_2LOG2E;
        } else if (tid < 256) {
            bvz_ws[tid - 128] = bv[tid - 128] * S_2LOG2E;
        }
        return;
    }
    // ---- q: 64 users per block (16 per wave) ----
    const int wv = tid >> 6, lane = tid & 63;
    const int l15 = lane & 15, quad = lane >> 4;
    const int u0 = (bx * 4 + wv) * 16;
    int ur = u0 + l15; if (ur >= U) ur = U - 1;
    const float* up = user_emb + (size_t)ur * 128 + quad * 8;
    bf16x8 af[4];
#pragma unroll
    for (int ks = 0; ks < 4; ++ks)
        af[ks] = pack2(*(const float4*)(up + ks * 32), *(const float4*)(up + ks * 32 + 4));
#pragma unroll
    for (int nt = 0; nt < 8; ++nt) {
        const int n = nt * 16 + l15;
        const float* wp = Wq + n * 128 + quad * 8;
        f32x4 acc = {0, 0, 0, 0};
#pragma unroll
        for (int ks = 0; ks < 4; ++ks) {
            bf16x8 bf = pack2(*(const float4*)(wp + ks * 32), *(const float4*)(wp + ks * 32 + 4));
            acc = MFMA16(af[ks], bf, acc);
        }
        const float bqv = bq[n];
#pragma unroll
        for (int r = 0; r < 4; ++r) {
            int row = u0 + quad * 4 + r;
            if (row < U) q_ws[row * 128 + nt * 16 + l15] = tanh_fast(acc[r] + bqv);
        }
    }
}

// =========================================================================
// Kernel 2 (main): ROUND-1 SKELETON (rolled nt loops -> VGPR ~48, all W in
// LDS, chained double-MFMA V pass, launch_bounds(1024,4) -> no spill; round
// 4 proved min-waves=8 + unroll => catastrophic scratch spill, WRITE_SIZE
// 20->415 MB). Register-neutral VALU cuts kept from round 3: (a) c init =
// pre-scaled bias with S folded into W (kills the scale-fma per element);
// (b) folded tanh: sum(q*tanh) = sum(q) - 2*sum(q*rcp) (kills the tanh
// final fma per element); (c) readfirstlane scalarizes job bookkeeping.
// =========================================================================
template<int BF16, int LC>
__global__ __launch_bounds__(1024, 4) void finerec_main(
    const float* __restrict__ item_table, const float* __restrict__ opin_table,
    const int* __restrict__ item_seqs, const int* __restrict__ opin_seqs,
    const float* __restrict__ q_ws, const float* __restrict__ bkz_ws,
    const float* __restrict__ bvz_ws, const short* __restrict__ wf_ws,
    const short* __restrict__ itb, const short* __restrict__ opb,
    float* __restrict__ out, int U, int Lrt)
{
    __shared__ __align__(16) short wlds[32768];   // S*Wk + S*Wv frag chunks
    __shared__ float bkz_lds[128], bvz_lds[128];

    const int L = LC ? LC : Lrt;
    const int tid = threadIdx.x;
    const int wv = tid >> 6, lane = tid & 63, l15 = lane & 15, quad = lane >> 4;

    const bf16x8* wsrc = (const bf16x8*)wf_ws;
    bf16x8* wldsv = (bf16x8*)wlds;
#pragma unroll
    for (int i = 0; i < 4; ++i)
        wldsv[i * 1024 + tid] = wsrc[i * 1024 + tid];
    if (tid < 128)      bkz_lds[tid]       = bkz_ws[tid];
    else if (tid < 256) bvz_lds[tid - 128] = bvz_ws[tid - 128];
    __syncthreads();   // the ONLY block barrier

    const int UL = U * L;
    const int njobs = (UL + 15) >> 4;
    const int nwaves = gridDim.x * 16;

#pragma unroll 1
    for (int job = blockIdx.x * 16 + wv; job < njobs; job += nwaves) {
        const int js = __builtin_amdgcn_readfirstlane(job);   // wave-uniform -> SALU
        const int g0 = js << 4;                  // first flattened row
        const int uA = g0 / L;
        const int bb = L - (g0 - uA * L);        // rows of uA in this job
        const bool split = (bb < 16) && (uA + 1 < U);

        int vi = 0, vo = 0;
        if (lane < 16 && g0 + lane < UL) {
            vi = item_seqs[g0 + lane];
            vo = opin_seqs[g0 + lane];
        }
        const unsigned long long mb = __ballot(vi > 0);

        // ---- gather item rows -> A-frags ----
        const int idx = __shfl(vi, l15);
        bf16x8 ai[4];
        if (BF16) {
            const bf16x8* pb = (const bf16x8*)itb + (size_t)idx * 16 + quad;
#pragma unroll
            for (int ks = 0; ks < 4; ++ks) ai[ks] = pb[ks * 4];
        } else {
            const float* p = item_table + (size_t)idx * 128 + quad * 8;
#pragma unroll
            for (int ks = 0; ks < 4; ++ks)
                ai[ks] = pack2(*(const float4*)(p + ks * 32), *(const float4*)(p + ks * 32 + 4));
        }

        const float* qpA = q_ws + (size_t)uA * 128;

        // ---- K pass: c init = bias; folded tanh: w = sum(q) - 2*sum(q*rcp) ----
        float wacc[4] = {0.0f, 0.0f, 0.0f, 0.0f};
        if (!split) {
            float sq = 0.0f;
#pragma unroll 1
            for (int nt = 0; nt < 8; ++nt) {
                const int n = nt * 16 + l15;
                const float qa = qpA[n];
                const float bz = bkz_lds[n];
                f32x4 c = {bz, bz, bz, bz};
#pragma unroll
                for (int ks = 0; ks < 4; ++ks)
                    c = MFMA16(ai[ks], wldsv[(n << 4) + ((ks * 4 + quad) ^ l15)], c);
                const float m2qa = -2.0f * qa;
                sq += qa;
#pragma unroll
                for (int r = 0; r < 4; ++r) {
                    const float rc = RCPF(EXP2F(c[r]) + 1.0f);
                    wacc[r] = fmaf(m2qa, rc, wacc[r]);
                }
            }
#pragma unroll
            for (int r = 0; r < 4; ++r) wacc[r] += sq;
        } else {
            float sqA = 0.0f, sqB = 0.0f;
#pragma unroll 1
            for (int nt = 0; nt < 8; ++nt) {
                const int n = nt * 16 + l15;
                const float qa  = qpA[n];
                const float qb2 = qpA[128 + n];
                const float bz = bkz_lds[n];
                f32x4 c = {bz, bz, bz, bz};
#pragma unroll
                for (int ks = 0; ks < 4; ++ks)
                    c = MFMA16(ai[ks], wldsv[(n << 4) + ((ks * 4 + quad) ^ l15)], c);
                const float m2qa = -2.0f * qa, m2qb = -2.0f * qb2;
                sqA += qa; sqB += qb2;
#pragma unroll
                for (int r = 0; r < 4; ++r) {
                    const float rc = RCPF(EXP2F(c[r]) + 1.0f);
                    wacc[r] = fmaf((quad * 4 + r < bb) ? m2qa : m2qb, rc, wacc[r]);
                }
            }
#pragma unroll
            for (int r = 0; r < 4; ++r) wacc[r] += (quad * 4 + r < bb) ? sqA : sqB;
        }
        // ---- w: reduce over 16 cols within quad + padding mask ----
        float w[4];
#pragma unroll
        for (int r = 0; r < 4; ++r) {
            float t = wacc[r];
            t += __shfl_xor(t, 1); t += __shfl_xor(t, 2);
            t += __shfl_xor(t, 4); t += __shfl_xor(t, 8);
            w[r] = ((mb >> (quad * 4 + r)) & 1ull) ? t : 0.0f;
        }
        // ---- gather opin rows -> second A-frags (chained MFMA linearity) ----
        const int od = __shfl(vo, l15);
        bf16x8 ao[4];
        if (BF16) {
            const bf16x8* pb = (const bf16x8*)opb + (size_t)od * 16 + quad;
#pragma unroll
            for (int ks = 0; ks < 4; ++ks) ao[ks] = pb[ks * 4];
        } else {
            const float* p = opin_table + (size_t)od * 128 + quad * 8;
#pragma unroll
            for (int ks = 0; ks < 4; ++ks)
                ao[ks] = pack2(*(const float4*)(p + ks * 32), *(const float4*)(p + ks * 32 + 4));
        }
        // ---- V pass: folded tanh: acc = sum(w) - 2*sum(w*rcp) ----
        float m2w[4]; float wsum = 0.0f;
#pragma unroll
        for (int r = 0; r < 4; ++r) { m2w[r] = -2.0f * w[r]; wsum += w[r]; }
        float* outbase = out + (size_t)uA * 128 + quad * 32 + l15;
        if (!split) {
            float s0 = 0.0f, s1 = 0.0f;
#pragma unroll 1
            for (int nt = 0; nt < 8; ++nt) {
                const int n = nt * 16 + l15;
                const float bz = bvz_lds[n];
                f32x4 c = {bz, bz, bz, bz};
#pragma unroll
                for (int ks = 0; ks < 4; ++ks) {
                    const bf16x8 wf = wldsv[2048 + (n << 4) + ((ks * 4 + quad) ^ l15)];
                    c = MFMA16(ai[ks], wf, c);
                    c = MFMA16(ao[ks], wf, c);
                }
                float acc = wsum;
#pragma unroll
                for (int r = 0; r < 4; ++r) {
                    const float rc = RCPF(EXP2F(c[r]) + 1.0f);
                    acc = fmaf(m2w[r], rc, acc);
                }
                acc += __shfl_xor(acc, 16);
                acc += __shfl_xor(acc, 32);
                const bool mine = (quad == (nt >> 1));
                s0 += (mine && !(nt & 1)) ? acc : 0.0f;
                s1 += (mine &&  (nt & 1)) ? acc : 0.0f;
            }
            atomicAdd(outbase, s0);
            atomicAdd(outbase + 16, s1);
        } else {
            float m2wA[4]; float wsA = 0.0f;
#pragma unroll
            for (int r = 0; r < 4; ++r) {
                const bool sA = (quad * 4 + r) < bb;
                m2wA[r] = sA ? m2w[r] : 0.0f;
                wsA += sA ? w[r] : 0.0f;
            }
            float sA0 = 0.0f, sA1 = 0.0f, sB0 = 0.0f, sB1 = 0.0f;
#pragma unroll 1
            for (int nt = 0; nt < 8; ++nt) {
                const int n = nt * 16 + l15;
                const float bz = bvz_lds[n];
                f32x4 c = {bz, bz, bz, bz};
#pragma unroll
                for (int ks = 0; ks < 4; ++ks) {
                    const bf16x8 wf = wldsv[2048 + (n << 4) + ((ks * 4 + quad) ^ l15)];
                    c = MFMA16(ai[ks], wf, c);
                    c = MFMA16(ao[ks], wf, c);
                }
                float accT = wsum, accA = wsA;
#pragma unroll
                for (int r = 0; r < 4; ++r) {
                    const float rc = RCPF(EXP2F(c[r]) + 1.0f);
                    accT = fmaf(m2w[r],  rc, accT);
                    accA = fmaf(m2wA[r], rc, accA);
                }
                accT += __shfl_xor(accT, 16); accT += __shfl_xor(accT, 32);
                accA += __shfl_xor(accA, 16); accA += __shfl_xor(accA, 32);
                const float accB = accT - accA;
                const bool mine = (quad == (nt >> 1));
                const bool lo = !(nt & 1);
                sA0 += (mine && lo)  ? accA : 0.0f;
                sA1 += (mine && !lo) ? accA : 0.0f;
                sB0 += (mine && lo)  ? accB : 0.0f;
                sB1 += (mine && !lo) ? accB : 0.0f;
            }
            atomicAdd(outbase, sA0);
            atomicAdd(outbase + 16, sA1);
            atomicAdd(outbase + 128, sB0);        // user uA+1
            atomicAdd(outbase + 144, sB1);
        }
    }
}

extern "C" void kernel_launch(void* const* d_in, const int* in_sizes, int n_in,
                              void* d_out, int out_size, void* d_ws, size_t ws_size,
                              hipStream_t stream) {
    const float* item_table = (const float*)d_in[0];
    const float* opin_table = (const float*)d_in[1];
    const float* user_emb   = (const float*)d_in[2];
    const float* attr       = (const float*)d_in[3];
    const float* Wq = (const float*)d_in[4];
    const float* bq = (const float*)d_in[5];
    const float* Wk = (const float*)d_in[6];
    const float* bk = (const float*)d_in[7];
    const float* Wv = (const float*)d_in[8];
    const float* bv = (const float*)d_in[9];
    const int* item_seqs = (const int*)d_in[10];
    const int* opin_seqs = (const int*)d_in[11];
    float* out = (float*)d_out;

    const int U = in_sizes[2] / 128;        // 10000
    const int L = in_sizes[10] / U;         // 50
    const int n_item = in_sizes[0] / 128;   // 50000
    const int n_opi  = in_sizes[1] / 128;   // 5000

    // ---- ws layout ----
    char* w = (char*)d_ws;
    float* q_ws   = (float*)w;               w += (size_t)U * 128 * 4;
    float* bkz_ws = (float*)w;               w += 512;
    float* bvz_ws = (float*)w;               w += 512;
    short* wf_ws  = (short*)w;               w += 4096 * 16;
    short* itb    = (short*)w;               w += (size_t)n_item * 128 * 2;
    short* opb    = (short*)w;               w += (size_t)n_opi * 128 * 2;
    const size_t need = (size_t)(w - (char*)d_ws);
    const int use_bf16 = (ws_size >= need) ? 1 : 0;

    const int qb = (U + 63) / 64;
    const int castb = use_bf16 ? (((n_item + n_opi) * 16 + 255) / 256) : 0;
    const int prep_grid = qb + 49 + castb;
    finerec_prep<<<prep_grid, 256, 0, stream>>>(
        user_emb, attr, Wq, bq, Wk, bk, Wv, bv, item_table, opin_table,
        q_ws, bkz_ws, bvz_ws, wf_ws, itb, opb, out, U, n_item, n_opi, qb);

    if (use_bf16) {
        if (L == 50)
            finerec_main<1, 50><<<512, 1024, 0, stream>>>(
                item_table, opin_table, item_seqs, opin_seqs,
                q_ws, bkz_ws, bvz_ws, wf_ws, itb, opb, out, U, L);
        else
            finerec_main<1, 0><<<512, 1024, 0, stream>>>(
                item_table, opin_table, item_seqs, opin_seqs,
                q_ws, bkz_ws, bvz_ws, wf_ws, itb, opb, out, U, L);
    } else {
        if (L == 50)
            finerec_main<0, 50><<<512, 1024, 0, stream>>>(
                item_table, opin_table, item_seqs, opin_seqs,
                q_ws, bkz_ws, bvz_ws, wf_ws, itb, opb, out, U, L);
        else
            finerec_main<0, 0><<<512, 1024, 0, stream>>>(
                item_table, opin_table, item_seqs, opin_seqs,
                q_ws, bkz_ws, bvz_ws, wf_ws, itb, opb, out, U, L);
    }
}